// Round 2
// baseline (795.215 us; speedup 1.0000x reference)
//
#include <hip/hip_runtime.h>
#include <math.h>

#define S 64
#define DIN 4
#define H 32
#define NHEADS 2
#define CF 16
#define DH 16
#define KV_STRIDE 20   // floats per LDS row: 16B-aligned; start banks spread over all 32

__global__ __launch_bounds__(64, 4)
void fused_fwd(const float* __restrict__ x,
               const float* __restrict__ c1w, const float* __restrict__ c1b,
               const float* __restrict__ c2w, const float* __restrict__ c2b,
               const float* __restrict__ cpw, const float* __restrict__ cpb,
               const float* __restrict__ ipw, const float* __restrict__ ipb,
               const float* __restrict__ wq, const float* __restrict__ bq,
               const float* __restrict__ wk, const float* __restrict__ bk,
               const float* __restrict__ wv, const float* __restrict__ bv,
               const float* __restrict__ wo, const float* __restrict__ bo,
               const float* __restrict__ lng, const float* __restrict__ lnb,
               const float* __restrict__ gw, const float* __restrict__ gb,
               const float* __restrict__ pw, const float* __restrict__ pb,
               const float* __restrict__ h1w, const float* __restrict__ h1b,
               const float* __restrict__ h2w, const float* __restrict__ h2b,
               float* __restrict__ out)
{
    // ONE time-shared staging buffer: k(head) -> v(head) (x2 heads) -> y halves
    __shared__ __attribute__((aligned(16))) float kv[S * KV_STRIDE];   // 5120 B
    __shared__ __attribute__((aligned(16))) float smc[192];            // 768 B

    const int b = blockIdx.x;
    const int s = threadIdx.x;   // sequence position, one wave per block

    // ---- load x row (coalesced float4) ----
    const float4 xr = reinterpret_cast<const float4*>(x)[b * S + s];
    float x0[4] = {xr.x, xr.y, xr.z, xr.w};

    // ================= Conv branch (register + shuffle only) =================
    float xm[4], xp[4];
#pragma unroll
    for (int i = 0; i < 4; ++i) {
        float up = __shfl_up(x0[i], 1);
        float dn = __shfl_down(x0[i], 1);
        xm[i] = (s > 0) ? up : 0.f;
        xp[i] = (s < S - 1) ? dn : 0.f;
    }
    float hc[CF];
#pragma unroll
    for (int o = 0; o < CF; ++o) {
        float acc = c1b[o];
#pragma unroll
        for (int i = 0; i < DIN; ++i) {
            acc += xm[i] * c1w[(o * DIN + i) * 3 + 0];
            acc += x0[i] * c1w[(o * DIN + i) * 3 + 1];
            acc += xp[i] * c1w[(o * DIN + i) * 3 + 2];
        }
        hc[o] = fmaxf(acc, 0.f);
    }
    float hm[CF], hp[CF];
#pragma unroll
    for (int o = 0; o < CF; ++o) {
        float up = __shfl_up(hc[o], 1);
        float dn = __shfl_down(hc[o], 1);
        hm[o] = (s > 0) ? up : 0.f;
        hp[o] = (s < S - 1) ? dn : 0.f;
    }
    float h2r[CF];
#pragma unroll
    for (int o = 0; o < CF; ++o) {
        float acc = c2b[o];
#pragma unroll
        for (int i = 0; i < CF; ++i) {
            acc += hm[i] * c2w[(o * CF + i) * 3 + 0];
            acc += hc[i] * c2w[(o * CF + i) * 3 + 1];
            acc += hp[i] * c2w[(o * CF + i) * 3 + 2];
        }
        h2r[o] = fmaxf(acc, 0.f);
    }
    // AdaptiveAvgPool1d over s: full-wave butterfly
#pragma unroll
    for (int o = 0; o < CF; ++o) {
        float v = h2r[o];
#pragma unroll
        for (int off = 32; off > 0; off >>= 1) v += __shfl_xor(v, off);
        h2r[o] = v * (1.f / 64.f);
    }
    if (s < H) {
        float acc = cpb[s];
#pragma unroll
        for (int o = 0; o < CF; ++o) acc += h2r[o] * cpw[s * CF + o];
        smc[s] = acc;   // conv_feat -> smc[0..31]
    }

    // ================= Attention branch =================
    // h = x @ ipw.T + ipb (weights wave-uniform -> scalar loads)
    float hr[H];
#pragma unroll
    for (int j = 0; j < H; ++j) {
        hr[j] = ipb[j] + x0[0] * ipw[j * 4 + 0] + x0[1] * ipw[j * 4 + 1]
                       + x0[2] * ipw[j * 4 + 2] + x0[3] * ipw[j * 4 + 3];
    }

    float attn_out[H];
#pragma unroll
    for (int j = 0; j < H; ++j) attn_out[j] = bo[j];

    for (int head = 0; head < NHEADS; ++head) {
        // ---- q row for this head (scale 1/sqrt(16) folded in) ----
        float qh[DH];
#pragma unroll
        for (int d = 0; d < DH; ++d) {
            const int j = head * DH + d;
            float acc = bq[j];
#pragma unroll
            for (int c = 0; c < H; ++c) acc += hr[c] * wq[j * H + c];
            qh[d] = acc * 0.25f;
        }

        // ---- k phase: stage this head's k rows into kv ----
        __syncthreads();   // prior buffer users done
#pragma unroll
        for (int j4 = 0; j4 < DH / 4; ++j4) {
            float4 kq;
            float* kqf = reinterpret_cast<float*>(&kq);
#pragma unroll
            for (int r = 0; r < 4; ++r) {
                const int j = head * DH + j4 * 4 + r;
                float kk = bk[j];
#pragma unroll
                for (int c = 0; c < H; ++c) kk += hr[c] * wk[j * H + c];
                kqf[r] = kk;
            }
            reinterpret_cast<float4*>(&kv[s * KV_STRIDE])[j4] = kq;
        }
        __syncthreads();

        // ---- scores (broadcast ds_read_b128) + stable softmax ----
        float sc[S];
        float mmax = -INFINITY;
#pragma unroll
        for (int kp = 0; kp < S; ++kp) {
            const float4* kr = reinterpret_cast<const float4*>(&kv[kp * KV_STRIDE]);
            float acc = 0.f;
#pragma unroll
            for (int dq = 0; dq < 4; ++dq) {
                float4 k4 = kr[dq];
                acc += qh[dq * 4 + 0] * k4.x + qh[dq * 4 + 1] * k4.y
                     + qh[dq * 4 + 2] * k4.z + qh[dq * 4 + 3] * k4.w;
            }
            sc[kp] = acc;
            mmax = fmaxf(mmax, acc);
        }
        float l = 0.f;
#pragma unroll
        for (int kp = 0; kp < S; ++kp) {
            float e = __expf(sc[kp] - mmax);
            sc[kp] = e;
            l += e;
        }
        const float inv = 1.f / l;

        // ---- v phase: overwrite kv with this head's v rows ----
        __syncthreads();   // all lanes done reading k
#pragma unroll
        for (int j4 = 0; j4 < DH / 4; ++j4) {
            float4 vq;
            float* vqf = reinterpret_cast<float*>(&vq);
#pragma unroll
            for (int r = 0; r < 4; ++r) {
                const int j = head * DH + j4 * 4 + r;
                float vv = bv[j];
#pragma unroll
                for (int c = 0; c < H; ++c) vv += hr[c] * wv[j * H + c];
                vqf[r] = vv;
            }
            reinterpret_cast<float4*>(&kv[s * KV_STRIDE])[j4] = vq;
        }
        __syncthreads();

        // ---- PV ----
        float ctx[DH];
#pragma unroll
        for (int d = 0; d < DH; ++d) ctx[d] = 0.f;
#pragma unroll
        for (int kp = 0; kp < S; ++kp) {
            const float4* vr = reinterpret_cast<const float4*>(&kv[kp * KV_STRIDE]);
            const float p = sc[kp];
#pragma unroll
            for (int dq = 0; dq < 4; ++dq) {
                float4 v4 = vr[dq];
                ctx[dq * 4 + 0] += p * v4.x;
                ctx[dq * 4 + 1] += p * v4.y;
                ctx[dq * 4 + 2] += p * v4.z;
                ctx[dq * 4 + 3] += p * v4.w;
            }
        }
#pragma unroll
        for (int d = 0; d < DH; ++d) ctx[d] *= inv;

        // attn_out += ctx_head @ wo[:, head*16 : head*16+16].T
#pragma unroll
        for (int j = 0; j < H; ++j) {
            float acc = attn_out[j];
#pragma unroll
            for (int d = 0; d < DH; ++d) acc += ctx[d] * wo[j * H + head * DH + d];
            attn_out[j] = acc;
        }
    }

    // ---- residual + LayerNorm over H ----
    float y[H];
    float mu = 0.f;
#pragma unroll
    for (int j = 0; j < H; ++j) { y[j] = hr[j] + attn_out[j]; mu += y[j]; }
    mu *= (1.f / 32.f);
    float var = 0.f;
#pragma unroll
    for (int j = 0; j < H; ++j) { float d = y[j] - mu; var += d * d; }
    var *= (1.f / 32.f);
    const float rstd = rsqrtf(var + 1e-5f);
#pragma unroll
    for (int j = 0; j < H; ++j) y[j] = (y[j] - mu) * rstd * lng[j] + lnb[j];

    // ---- att_feat = mean over s: two 16-col passes through kv buffer ----
#pragma unroll
    for (int hh = 0; hh < 2; ++hh) {
        __syncthreads();   // previous kv users done
#pragma unroll
        for (int j4 = 0; j4 < 4; ++j4) {
            float4 t;
            t.x = y[hh * 16 + j4 * 4 + 0];
            t.y = y[hh * 16 + j4 * 4 + 1];
            t.z = y[hh * 16 + j4 * 4 + 2];
            t.w = y[hh * 16 + j4 * 4 + 3];
            reinterpret_cast<float4*>(&kv[s * KV_STRIDE])[j4] = t;
        }
        __syncthreads();
        const int g = s >> 4, j = s & 15;
        float p = 0.f;
#pragma unroll
        for (int r = 0; r < 16; ++r) p += kv[(g * 16 + r) * KV_STRIDE + j];
        p += __shfl_xor(p, 16);
        p += __shfl_xor(p, 32);
        if (s < 16) smc[H + hh * 16 + s] = p * (1.f / 64.f);   // att_feat -> smc[32..63]
    }
    __syncthreads();

    // ================= DBMM fusion =================
    {
        const int j = s;   // all 64 lanes
        float acc = gb[j];
        const float4* smc4 = reinterpret_cast<const float4*>(smc);
        const float4* gw4  = reinterpret_cast<const float4*>(&gw[j * 2 * H]);
#pragma unroll
        for (int k4 = 0; k4 < 16; ++k4) {
            float4 cv = smc4[k4];
            float4 wv4 = gw4[k4];
            acc += cv.x * wv4.x + cv.y * wv4.y + cv.z * wv4.z + cv.w * wv4.w;
        }
        const float sig = 1.f / (1.f + __expf(-acc));
        smc[64 + j] = smc[j] * sig;        // gated
    }
    __syncthreads();
    if (s < H) {
        float acc = pb[s];
        const float4* smc4 = reinterpret_cast<const float4*>(smc + 64);
        const float4* pw4  = reinterpret_cast<const float4*>(&pw[s * 2 * H]);
#pragma unroll
        for (int k4 = 0; k4 < 16; ++k4) {
            float4 cv = smc4[k4];
            float4 wv4 = pw4[k4];
            acc += cv.x * wv4.x + cv.y * wv4.y + cv.z * wv4.z + cv.w * wv4.w;
        }
        smc[128 + s] = acc;                // fused
    }
    __syncthreads();

    // ================= Output head =================
    if (s < 16) {
        float acc = h1b[s];
#pragma unroll
        for (int c = 0; c < H; ++c) acc += smc[128 + c] * h1w[s * H + c];
        smc[160 + s] = fmaxf(acc, 0.f);    // t1
    }
    __syncthreads();
    if (s < 2) {
        float acc = h2b[s];
#pragma unroll
        for (int c = 0; c < 16; ++c) acc += smc[160 + c] * h2w[s * 16 + c];
        out[b * 2 + s] = acc;
    }
}

extern "C" void kernel_launch(void* const* d_in, const int* in_sizes, int n_in,
                              void* d_out, int out_size, void* d_ws, size_t ws_size,
                              hipStream_t stream) {
    (void)n_in; (void)d_ws; (void)ws_size;
    const int nb = out_size / 2;   // B
    const float* xp_ = (const float*)d_in[0];
    const float* c1w = (const float*)d_in[1];  const float* c1b = (const float*)d_in[2];
    const float* c2w = (const float*)d_in[3];  const float* c2b = (const float*)d_in[4];
    const float* cpw = (const float*)d_in[5];  const float* cpb = (const float*)d_in[6];
    const float* ipw = (const float*)d_in[7];  const float* ipb = (const float*)d_in[8];
    const float* wq  = (const float*)d_in[9];  const float* bq  = (const float*)d_in[10];
    const float* wk  = (const float*)d_in[11]; const float* bk  = (const float*)d_in[12];
    const float* wv  = (const float*)d_in[13]; const float* bv  = (const float*)d_in[14];
    const float* wo  = (const float*)d_in[15]; const float* bo  = (const float*)d_in[16];
    const float* lng = (const float*)d_in[17]; const float* lnb = (const float*)d_in[18];
    const float* gw  = (const float*)d_in[19]; const float* gb  = (const float*)d_in[20];
    const float* pw  = (const float*)d_in[21]; const float* pb  = (const float*)d_in[22];
    const float* h1w = (const float*)d_in[23]; const float* h1b = (const float*)d_in[24];
    const float* h2w = (const float*)d_in[25]; const float* h2b = (const float*)d_in[26];
    float* outp = (float*)d_out;

    dim3 grid(nb), block(64);
    hipLaunchKernelGGL(fused_fwd, grid, block, 0, stream,
                       xp_, c1w, c1b, c2w, c2b, cpw, cpb, ipw, ipb,
                       wq, bq, wk, bk, wv, bv, wo, bo, lng, lnb,
                       gw, gb, pw, pb, h1w, h1b, h2w, h2b, outp);
}

// Round 3
// 759.410 us; speedup vs baseline: 1.0471x; 1.0471x over previous
//
#include <hip/hip_runtime.h>
#include <math.h>

#define S 64
#define DIN 4
#define H 32
#define NHEADS 2
#define CF 16
#define DH 16
#define KV_STRIDE 20   // floats per LDS row: 16B-aligned; start banks spread over all 32

__global__ __launch_bounds__(64, 2)
void fused_fwd(const float* __restrict__ x,
               const float* __restrict__ c1w, const float* __restrict__ c1b,
               const float* __restrict__ c2w, const float* __restrict__ c2b,
               const float* __restrict__ cpw, const float* __restrict__ cpb,
               const float* __restrict__ ipw, const float* __restrict__ ipb,
               const float* __restrict__ wq, const float* __restrict__ bq,
               const float* __restrict__ wk, const float* __restrict__ bk,
               const float* __restrict__ wv, const float* __restrict__ bv,
               const float* __restrict__ wo, const float* __restrict__ bo,
               const float* __restrict__ lng, const float* __restrict__ lnb,
               const float* __restrict__ gw, const float* __restrict__ gb,
               const float* __restrict__ pw, const float* __restrict__ pb,
               const float* __restrict__ h1w, const float* __restrict__ h1b,
               const float* __restrict__ h2w, const float* __restrict__ h2b,
               float* __restrict__ out)
{
    // ONE time-shared staging buffer: k(head) -> v(head) (x2 heads) -> y halves
    __shared__ __attribute__((aligned(16))) float kv[S * KV_STRIDE];   // 5120 B
    __shared__ __attribute__((aligned(16))) float smc[192];            // 768 B

    const int b = blockIdx.x;
    const int s = threadIdx.x;   // sequence position, one wave per block

    // ---- load x row (coalesced float4) ----
    const float4 xr = reinterpret_cast<const float4*>(x)[b * S + s];
    float x0[4] = {xr.x, xr.y, xr.z, xr.w};

    // ================= Conv branch (register + shuffle only) =================
    float xm[4], xp[4];
#pragma unroll
    for (int i = 0; i < 4; ++i) {
        float up = __shfl_up(x0[i], 1);
        float dn = __shfl_down(x0[i], 1);
        xm[i] = (s > 0) ? up : 0.f;
        xp[i] = (s < S - 1) ? dn : 0.f;
    }
    float hc[CF];
#pragma unroll
    for (int o = 0; o < CF; ++o) {
        float acc = c1b[o];
#pragma unroll
        for (int i = 0; i < DIN; ++i) {
            acc += xm[i] * c1w[(o * DIN + i) * 3 + 0];
            acc += x0[i] * c1w[(o * DIN + i) * 3 + 1];
            acc += xp[i] * c1w[(o * DIN + i) * 3 + 2];
        }
        hc[o] = fmaxf(acc, 0.f);
    }
    float hm[CF], hp[CF];
#pragma unroll
    for (int o = 0; o < CF; ++o) {
        float up = __shfl_up(hc[o], 1);
        float dn = __shfl_down(hc[o], 1);
        hm[o] = (s > 0) ? up : 0.f;
        hp[o] = (s < S - 1) ? dn : 0.f;
    }
    float h2r[CF];
#pragma unroll
    for (int o = 0; o < CF; ++o) {
        float acc = c2b[o];
#pragma unroll
        for (int i = 0; i < CF; ++i) {
            acc += hm[i] * c2w[(o * CF + i) * 3 + 0];
            acc += hc[i] * c2w[(o * CF + i) * 3 + 1];
            acc += hp[i] * c2w[(o * CF + i) * 3 + 2];
        }
        h2r[o] = fmaxf(acc, 0.f);
    }
    // AdaptiveAvgPool1d over s: full-wave butterfly
#pragma unroll
    for (int o = 0; o < CF; ++o) {
        float v = h2r[o];
#pragma unroll
        for (int off = 32; off > 0; off >>= 1) v += __shfl_xor(v, off);
        h2r[o] = v * (1.f / 64.f);
    }
    if (s < H) {
        float acc = cpb[s];
#pragma unroll
        for (int o = 0; o < CF; ++o) acc += h2r[o] * cpw[s * CF + o];
        smc[s] = acc;   // conv_feat -> smc[0..31]
    }

    // ================= Attention branch =================
    // h = x @ ipw.T + ipb (weights wave-uniform -> scalar loads)
    float hr[H];
#pragma unroll
    for (int j = 0; j < H; ++j) {
        hr[j] = ipb[j] + x0[0] * ipw[j * 4 + 0] + x0[1] * ipw[j * 4 + 1]
                       + x0[2] * ipw[j * 4 + 2] + x0[3] * ipw[j * 4 + 3];
    }

    float attn_out[H];
#pragma unroll
    for (int j = 0; j < H; ++j) attn_out[j] = bo[j];

    for (int head = 0; head < NHEADS; ++head) {
        // ---- q row for this head (scale 1/sqrt(16) folded in) ----
        float qh[DH];
#pragma unroll
        for (int d = 0; d < DH; ++d) {
            const int j = head * DH + d;
            float acc = bq[j];
#pragma unroll
            for (int c = 0; c < H; ++c) acc += hr[c] * wq[j * H + c];
            qh[d] = acc * 0.25f;
        }

        // ---- k phase: stage this head's k rows into kv ----
        __syncthreads();   // prior buffer users done
#pragma unroll
        for (int j4 = 0; j4 < DH / 4; ++j4) {
            float4 kq;
            float* kqf = reinterpret_cast<float*>(&kq);
#pragma unroll
            for (int r = 0; r < 4; ++r) {
                const int j = head * DH + j4 * 4 + r;
                float kk = bk[j];
#pragma unroll
                for (int c = 0; c < H; ++c) kk += hr[c] * wk[j * H + c];
                kqf[r] = kk;
            }
            reinterpret_cast<float4*>(&kv[s * KV_STRIDE])[j4] = kq;
        }
        __syncthreads();

        // ---- scores (broadcast ds_read_b128) + stable softmax ----
        float sc[S];
        float mmax = -INFINITY;
#pragma unroll
        for (int kp = 0; kp < S; ++kp) {
            const float4* kr = reinterpret_cast<const float4*>(&kv[kp * KV_STRIDE]);
            float acc = 0.f;
#pragma unroll
            for (int dq = 0; dq < 4; ++dq) {
                float4 k4 = kr[dq];
                acc += qh[dq * 4 + 0] * k4.x + qh[dq * 4 + 1] * k4.y
                     + qh[dq * 4 + 2] * k4.z + qh[dq * 4 + 3] * k4.w;
            }
            sc[kp] = acc;
            mmax = fmaxf(mmax, acc);
        }
        float l = 0.f;
#pragma unroll
        for (int kp = 0; kp < S; ++kp) {
            float e = __expf(sc[kp] - mmax);
            sc[kp] = e;
            l += e;
        }
        const float inv = 1.f / l;

        // ---- v phase: overwrite kv with this head's v rows ----
        __syncthreads();   // all lanes done reading k
#pragma unroll
        for (int j4 = 0; j4 < DH / 4; ++j4) {
            float4 vq;
            float* vqf = reinterpret_cast<float*>(&vq);
#pragma unroll
            for (int r = 0; r < 4; ++r) {
                const int j = head * DH + j4 * 4 + r;
                float vv = bv[j];
#pragma unroll
                for (int c = 0; c < H; ++c) vv += hr[c] * wv[j * H + c];
                vqf[r] = vv;
            }
            reinterpret_cast<float4*>(&kv[s * KV_STRIDE])[j4] = vq;
        }
        __syncthreads();

        // ---- PV ----
        float ctx[DH];
#pragma unroll
        for (int d = 0; d < DH; ++d) ctx[d] = 0.f;
#pragma unroll
        for (int kp = 0; kp < S; ++kp) {
            const float4* vr = reinterpret_cast<const float4*>(&kv[kp * KV_STRIDE]);
            const float p = sc[kp];
#pragma unroll
            for (int dq = 0; dq < 4; ++dq) {
                float4 v4 = vr[dq];
                ctx[dq * 4 + 0] += p * v4.x;
                ctx[dq * 4 + 1] += p * v4.y;
                ctx[dq * 4 + 2] += p * v4.z;
                ctx[dq * 4 + 3] += p * v4.w;
            }
        }
#pragma unroll
        for (int d = 0; d < DH; ++d) ctx[d] *= inv;

        // attn_out += ctx_head @ wo[:, head*16 : head*16+16].T
#pragma unroll
        for (int j = 0; j < H; ++j) {
            float acc = attn_out[j];
#pragma unroll
            for (int d = 0; d < DH; ++d) acc += ctx[d] * wo[j * H + head * DH + d];
            attn_out[j] = acc;
        }
    }

    // ---- residual + LayerNorm over H ----
    float y[H];
    float mu = 0.f;
#pragma unroll
    for (int j = 0; j < H; ++j) { y[j] = hr[j] + attn_out[j]; mu += y[j]; }
    mu *= (1.f / 32.f);
    float var = 0.f;
#pragma unroll
    for (int j = 0; j < H; ++j) { float d = y[j] - mu; var += d * d; }
    var *= (1.f / 32.f);
    const float rstd = rsqrtf(var + 1e-5f);
#pragma unroll
    for (int j = 0; j < H; ++j) y[j] = (y[j] - mu) * rstd * lng[j] + lnb[j];

    // ---- att_feat = mean over s: two 16-col passes through kv buffer ----
#pragma unroll
    for (int hh = 0; hh < 2; ++hh) {
        __syncthreads();   // previous kv users done
#pragma unroll
        for (int j4 = 0; j4 < 4; ++j4) {
            float4 t;
            t.x = y[hh * 16 + j4 * 4 + 0];
            t.y = y[hh * 16 + j4 * 4 + 1];
            t.z = y[hh * 16 + j4 * 4 + 2];
            t.w = y[hh * 16 + j4 * 4 + 3];
            reinterpret_cast<float4*>(&kv[s * KV_STRIDE])[j4] = t;
        }
        __syncthreads();
        const int g = s >> 4, j = s & 15;
        float p = 0.f;
#pragma unroll
        for (int r = 0; r < 16; ++r) p += kv[(g * 16 + r) * KV_STRIDE + j];
        p += __shfl_xor(p, 16);
        p += __shfl_xor(p, 32);
        if (s < 16) smc[H + hh * 16 + s] = p * (1.f / 64.f);   // att_feat -> smc[32..63]
    }
    __syncthreads();

    // ================= DBMM fusion =================
    {
        const int j = s;   // all 64 lanes
        float acc = gb[j];
        const float4* smc4 = reinterpret_cast<const float4*>(smc);
        const float4* gw4  = reinterpret_cast<const float4*>(&gw[j * 2 * H]);
#pragma unroll
        for (int k4 = 0; k4 < 16; ++k4) {
            float4 cv = smc4[k4];
            float4 wv4 = gw4[k4];
            acc += cv.x * wv4.x + cv.y * wv4.y + cv.z * wv4.z + cv.w * wv4.w;
        }
        const float sig = 1.f / (1.f + __expf(-acc));
        smc[64 + j] = smc[j] * sig;        // gated
    }
    __syncthreads();
    if (s < H) {
        float acc = pb[s];
        const float4* smc4 = reinterpret_cast<const float4*>(smc + 64);
        const float4* pw4  = reinterpret_cast<const float4*>(&pw[s * 2 * H]);
#pragma unroll
        for (int k4 = 0; k4 < 16; ++k4) {
            float4 cv = smc4[k4];
            float4 wv4 = pw4[k4];
            acc += cv.x * wv4.x + cv.y * wv4.y + cv.z * wv4.z + cv.w * wv4.w;
        }
        smc[128 + s] = acc;                // fused
    }
    __syncthreads();

    // ================= Output head =================
    if (s < 16) {
        float acc = h1b[s];
#pragma unroll
        for (int c = 0; c < H; ++c) acc += smc[128 + c] * h1w[s * H + c];
        smc[160 + s] = fmaxf(acc, 0.f);    // t1
    }
    __syncthreads();
    if (s < 2) {
        float acc = h2b[s];
#pragma unroll
        for (int c = 0; c < 16; ++c) acc += smc[160 + c] * h2w[s * 16 + c];
        out[b * 2 + s] = acc;
    }
}

extern "C" void kernel_launch(void* const* d_in, const int* in_sizes, int n_in,
                              void* d_out, int out_size, void* d_ws, size_t ws_size,
                              hipStream_t stream) {
    (void)n_in; (void)d_ws; (void)ws_size;
    const int nb = out_size / 2;   // B
    const float* xp_ = (const float*)d_in[0];
    const float* c1w = (const float*)d_in[1];  const float* c1b = (const float*)d_in[2];
    const float* c2w = (const float*)d_in[3];  const float* c2b = (const float*)d_in[4];
    const float* cpw = (const float*)d_in[5];  const float* cpb = (const float*)d_in[6];
    const float* ipw = (const float*)d_in[7];  const float* ipb = (const float*)d_in[8];
    const float* wq  = (const float*)d_in[9];  const float* bq  = (const float*)d_in[10];
    const float* wk  = (const float*)d_in[11]; const float* bk  = (const float*)d_in[12];
    const float* wv  = (const float*)d_in[13]; const float* bv  = (const float*)d_in[14];
    const float* wo  = (const float*)d_in[15]; const float* bo  = (const float*)d_in[16];
    const float* lng = (const float*)d_in[17]; const float* lnb = (const float*)d_in[18];
    const float* gw  = (const float*)d_in[19]; const float* gb  = (const float*)d_in[20];
    const float* pw  = (const float*)d_in[21]; const float* pb  = (const float*)d_in[22];
    const float* h1w = (const float*)d_in[23]; const float* h1b = (const float*)d_in[24];
    const float* h2w = (const float*)d_in[25]; const float* h2b = (const float*)d_in[26];
    float* outp = (float*)d_out;

    dim3 grid(nb), block(64);
    hipLaunchKernelGGL(fused_fwd, grid, block, 0, stream,
                       xp_, c1w, c1b, c2w, c2b, cpw, cpb, ipw, ipb,
                       wq, bq, wk, bk, wv, bv, wo, bo, lng, lnb,
                       gw, gb, pw, pb, h1w, h1b, h2w, h2b, outp);
}

// Round 4
// 740.882 us; speedup vs baseline: 1.0733x; 1.0250x over previous
//
#include <hip/hip_runtime.h>
#include <math.h>

#define S 64
#define DIN 4
#define H 32
#define NHEADS 2
#define CF 16
#define DH 16
#define ROW 36   // LDS row stride (floats): 144 B, 16B-aligned, broadcast reads conflict-free

__global__ __launch_bounds__(64)
void fused_fwd(const float* __restrict__ x,
               const float* __restrict__ c1w, const float* __restrict__ c1b,
               const float* __restrict__ c2w, const float* __restrict__ c2b,
               const float* __restrict__ cpw, const float* __restrict__ cpb,
               const float* __restrict__ ipw, const float* __restrict__ ipb,
               const float* __restrict__ wq, const float* __restrict__ bq,
               const float* __restrict__ wk, const float* __restrict__ bk,
               const float* __restrict__ wv, const float* __restrict__ bv,
               const float* __restrict__ wo, const float* __restrict__ bo,
               const float* __restrict__ lng, const float* __restrict__ lnb,
               const float* __restrict__ gw, const float* __restrict__ gb,
               const float* __restrict__ pw, const float* __restrict__ pb,
               const float* __restrict__ h1w, const float* __restrict__ h1b,
               const float* __restrict__ h2w, const float* __restrict__ h2b,
               float* __restrict__ out)
{
    // time-shared: per-head {k|v} rows -> y rows for the mean
    __shared__ __attribute__((aligned(16))) float kv[S * ROW];   // 9216 B
    __shared__ float smc[192];                                   // 768 B

    const int b = blockIdx.x;
    const int s = threadIdx.x;   // sequence position; one wave per block

    // ---- load x row (coalesced float4) ----
    const float4 xr = reinterpret_cast<const float4*>(x)[b * S + s];
    float x0[4] = {xr.x, xr.y, xr.z, xr.w};

    // ================= Conv branch (register + shuffle only) =================
    float xm[4], xp[4];
#pragma unroll
    for (int i = 0; i < 4; ++i) {
        float up = __shfl_up(x0[i], 1);
        float dn = __shfl_down(x0[i], 1);
        xm[i] = (s > 0) ? up : 0.f;
        xp[i] = (s < S - 1) ? dn : 0.f;
    }
    float hc[CF];
#pragma unroll
    for (int o = 0; o < CF; ++o) {
        float acc = c1b[o];
#pragma unroll
        for (int i = 0; i < DIN; ++i) {
            acc += xm[i] * c1w[(o * DIN + i) * 3 + 0];
            acc += x0[i] * c1w[(o * DIN + i) * 3 + 1];
            acc += xp[i] * c1w[(o * DIN + i) * 3 + 2];
        }
        hc[o] = fmaxf(acc, 0.f);
    }
    float hm[CF], hp[CF];
#pragma unroll
    for (int o = 0; o < CF; ++o) {
        float up = __shfl_up(hc[o], 1);
        float dn = __shfl_down(hc[o], 1);
        hm[o] = (s > 0) ? up : 0.f;
        hp[o] = (s < S - 1) ? dn : 0.f;
    }
    float h2r[CF];
#pragma unroll
    for (int o = 0; o < CF; ++o) {
        float acc = c2b[o];
#pragma unroll
        for (int i = 0; i < CF; ++i) {
            acc += hm[i] * c2w[(o * CF + i) * 3 + 0];
            acc += hc[i] * c2w[(o * CF + i) * 3 + 1];
            acc += hp[i] * c2w[(o * CF + i) * 3 + 2];
        }
        h2r[o] = fmaxf(acc, 0.f);
    }
    // AdaptiveAvgPool1d over s: full-wave butterfly
#pragma unroll
    for (int o = 0; o < CF; ++o) {
        float v = h2r[o];
#pragma unroll
        for (int off = 32; off > 0; off >>= 1) v += __shfl_xor(v, off);
        h2r[o] = v * (1.f / 64.f);
    }
    if (s < H) {
        float acc = cpb[s];
#pragma unroll
        for (int o = 0; o < CF; ++o) acc += h2r[o] * cpw[s * CF + o];
        smc[s] = acc;   // conv_feat -> smc[0..31]
    }

    // ================= Attention branch =================
    // h = x @ ipw.T + ipb (weights wave-uniform -> scalar loads)
    float hr[H];
#pragma unroll
    for (int j = 0; j < H; ++j) {
        hr[j] = ipb[j] + x0[0] * ipw[j * 4 + 0] + x0[1] * ipw[j * 4 + 1]
                       + x0[2] * ipw[j * 4 + 2] + x0[3] * ipw[j * 4 + 3];
    }

    float attn_out[H];
#pragma unroll
    for (int j = 0; j < H; ++j) attn_out[j] = bo[j];

#pragma unroll
    for (int head = 0; head < NHEADS; ++head) {
        // ---- stage k|v rows for this head: row = [k0..k15 | v0..v15 | pad] ----
#pragma unroll
        for (int j4 = 0; j4 < DH / 4; ++j4) {
            float4 kq;
            float* kqf = reinterpret_cast<float*>(&kq);
#pragma unroll
            for (int r = 0; r < 4; ++r) {
                const int j = head * DH + j4 * 4 + r;
                float kk = bk[j];
#pragma unroll
                for (int c = 0; c < H; ++c) kk += hr[c] * wk[j * H + c];
                kqf[r] = kk;
            }
            reinterpret_cast<float4*>(&kv[s * ROW])[j4] = kq;
        }
#pragma unroll
        for (int j4 = 0; j4 < DH / 4; ++j4) {
            float4 vq;
            float* vqf = reinterpret_cast<float*>(&vq);
#pragma unroll
            for (int r = 0; r < 4; ++r) {
                const int j = head * DH + j4 * 4 + r;
                float vv = bv[j];
#pragma unroll
                for (int c = 0; c < H; ++c) vv += hr[c] * wv[j * H + c];
                vqf[r] = vv;
            }
            reinterpret_cast<float4*>(&kv[s * ROW + DH])[j4] = vq;
        }

        // ---- q row for this head (1/sqrt(16) folded); overlaps the LDS-write drain ----
        float qh[DH];
#pragma unroll
        for (int d = 0; d < DH; ++d) {
            const int j = head * DH + d;
            float acc = bq[j];
#pragma unroll
            for (int c = 0; c < H; ++c) acc += hr[c] * wq[j * H + c];
            qh[d] = acc * 0.25f;
        }
        __syncthreads();

        // ---- fused QK -> exp -> PV sweep (no max pass: |score| << 1 by construction) ----
        float l = 0.f;
        float ctx[DH];
#pragma unroll
        for (int d = 0; d < DH; ++d) ctx[d] = 0.f;
#pragma unroll 8
        for (int kp = 0; kp < S; ++kp) {
            const float4* r = reinterpret_cast<const float4*>(&kv[kp * ROW]);
            float sc = 0.f;
#pragma unroll
            for (int dq = 0; dq < 4; ++dq) {
                float4 k4 = r[dq];
                sc += qh[dq * 4 + 0] * k4.x + qh[dq * 4 + 1] * k4.y
                    + qh[dq * 4 + 2] * k4.z + qh[dq * 4 + 3] * k4.w;
            }
            const float e = __expf(sc);
            l += e;
#pragma unroll
            for (int dq = 0; dq < 4; ++dq) {
                float4 v4 = r[4 + dq];
                ctx[dq * 4 + 0] += e * v4.x;
                ctx[dq * 4 + 1] += e * v4.y;
                ctx[dq * 4 + 2] += e * v4.z;
                ctx[dq * 4 + 3] += e * v4.w;
            }
        }
        const float inv = 1.f / l;
#pragma unroll
        for (int d = 0; d < DH; ++d) ctx[d] *= inv;

        // attn_out += ctx_head @ wo[:, head*16 : head*16+16].T
#pragma unroll
        for (int j = 0; j < H; ++j) {
            float acc = attn_out[j];
#pragma unroll
            for (int d = 0; d < DH; ++d) acc += ctx[d] * wo[j * H + head * DH + d];
            attn_out[j] = acc;
        }
        __syncthreads();   // all lanes done reading kv before it is overwritten
    }

    // ---- residual + LayerNorm over H ----
    float y[H];
    float mu = 0.f;
#pragma unroll
    for (int j = 0; j < H; ++j) { y[j] = hr[j] + attn_out[j]; mu += y[j]; }
    mu *= (1.f / 32.f);
    float var = 0.f;
#pragma unroll
    for (int j = 0; j < H; ++j) { float d = y[j] - mu; var += d * d; }
    var *= (1.f / 32.f);
    const float rstd = rsqrtf(var + 1e-5f);
#pragma unroll
    for (int j = 0; j < H; ++j) y[j] = (y[j] - mu) * rstd * lng[j] + lnb[j];

    // ---- att_feat = mean over s: single 32-col pass through kv ----
#pragma unroll
    for (int j4 = 0; j4 < H / 4; ++j4) {
        float4 t;
        t.x = y[j4 * 4 + 0]; t.y = y[j4 * 4 + 1];
        t.z = y[j4 * 4 + 2]; t.w = y[j4 * 4 + 3];
        reinterpret_cast<float4*>(&kv[s * ROW])[j4] = t;
    }
    __syncthreads();
    {
        const int g = s >> 5, j = s & 31;     // two row-groups of 32
        float p = 0.f;
#pragma unroll 8
        for (int r = 0; r < 32; ++r) p += kv[(g * 32 + r) * ROW + j];
        p += __shfl_xor(p, 32);               // combine the two groups
        if (s < H) smc[H + s] = p * (1.f / 64.f);   // att_feat -> smc[32..63]
    }
    __syncthreads();

    // ================= DBMM fusion =================
    {
        const int j = s;   // all 64 lanes
        float acc = gb[j];
        const float4* smc4 = reinterpret_cast<const float4*>(smc);
        const float4* gw4  = reinterpret_cast<const float4*>(&gw[j * 2 * H]);
#pragma unroll
        for (int k4 = 0; k4 < 16; ++k4) {
            float4 cv = smc4[k4];
            float4 wv4 = gw4[k4];
            acc += cv.x * wv4.x + cv.y * wv4.y + cv.z * wv4.z + cv.w * wv4.w;
        }
        const float sig = 1.f / (1.f + __expf(-acc));
        smc[64 + j] = smc[j] * sig;        // gated
    }
    __syncthreads();
    if (s < H) {
        float acc = pb[s];
        const float4* smc4 = reinterpret_cast<const float4*>(smc + 64);
        const float4* pw4  = reinterpret_cast<const float4*>(&pw[s * 2 * H]);
#pragma unroll
        for (int k4 = 0; k4 < 16; ++k4) {
            float4 cv = smc4[k4];
            float4 wv4 = pw4[k4];
            acc += cv.x * wv4.x + cv.y * wv4.y + cv.z * wv4.z + cv.w * wv4.w;
        }
        smc[128 + s] = acc;                // fused
    }
    __syncthreads();

    // ================= Output head =================
    if (s < 16) {
        float acc = h1b[s];
#pragma unroll
        for (int c = 0; c < H; ++c) acc += smc[128 + c] * h1w[s * H + c];
        smc[160 + s] = fmaxf(acc, 0.f);    // t1
    }
    __syncthreads();
    if (s < 2) {
        float acc = h2b[s];
#pragma unroll
        for (int c = 0; c < 16; ++c) acc += smc[160 + c] * h2w[s * 16 + c];
        out[b * 2 + s] = acc;
    }
}

extern "C" void kernel_launch(void* const* d_in, const int* in_sizes, int n_in,
                              void* d_out, int out_size, void* d_ws, size_t ws_size,
                              hipStream_t stream) {
    (void)n_in; (void)d_ws; (void)ws_size;
    const int nb = out_size / 2;   // B
    const float* xp_ = (const float*)d_in[0];
    const float* c1w = (const float*)d_in[1];  const float* c1b = (const float*)d_in[2];
    const float* c2w = (const float*)d_in[3];  const float* c2b = (const float*)d_in[4];
    const float* cpw = (const float*)d_in[5];  const float* cpb = (const float*)d_in[6];
    const float* ipw = (const float*)d_in[7];  const float* ipb = (const float*)d_in[8];
    const float* wq  = (const float*)d_in[9];  const float* bq  = (const float*)d_in[10];
    const float* wk  = (const float*)d_in[11]; const float* bk  = (const float*)d_in[12];
    const float* wv  = (const float*)d_in[13]; const float* bv  = (const float*)d_in[14];
    const float* wo  = (const float*)d_in[15]; const float* bo  = (const float*)d_in[16];
    const float* lng = (const float*)d_in[17]; const float* lnb = (const float*)d_in[18];
    const float* gw  = (const float*)d_in[19]; const float* gb  = (const float*)d_in[20];
    const float* pw  = (const float*)d_in[21]; const float* pb  = (const float*)d_in[22];
    const float* h1w = (const float*)d_in[23]; const float* h1b = (const float*)d_in[24];
    const float* h2w = (const float*)d_in[25]; const float* h2b = (const float*)d_in[26];
    float* outp = (float*)d_out;

    dim3 grid(nb), block(64);
    hipLaunchKernelGGL(fused_fwd, grid, block, 0, stream,
                       xp_, c1w, c1b, c2w, c2b, cpw, cpb, ipw, ipb,
                       wq, bq, wk, bk, wv, bv, wo, bo, lng, lnb,
                       gw, gb, pw, pb, h1w, h1b, h2w, h2b, outp);
}

// Round 5
// 716.061 us; speedup vs baseline: 1.1105x; 1.0347x over previous
//
#include <hip/hip_runtime.h>
#include <math.h>

#define S 64
#define DIN 4
#define H 32
#define NHEADS 2
#define CF 16
#define DH 16
#define ROW 36        // LDS row stride (floats): 144 B, 16B-aligned; (4s+c)%32 spreads banks
#define WPB 4         // waves (batch elements) per block

// Wave-local "barrier": compiler ordering fence only. Within a single wave the
// LDS pipe processes ds ops in order, so no s_barrier / vmcnt drain is needed.
__device__ __forceinline__ void wsync() {
    asm volatile("" ::: "memory");
    __builtin_amdgcn_wave_barrier();
    asm volatile("" ::: "memory");
}

__global__ __launch_bounds__(WPB * 64)
void fused_fwd(const float* __restrict__ x,
               const float* __restrict__ c1w, const float* __restrict__ c1b,
               const float* __restrict__ c2w, const float* __restrict__ c2b,
               const float* __restrict__ cpw, const float* __restrict__ cpb,
               const float* __restrict__ ipw, const float* __restrict__ ipb,
               const float* __restrict__ wq, const float* __restrict__ bq,
               const float* __restrict__ wk, const float* __restrict__ bk,
               const float* __restrict__ wv, const float* __restrict__ bv,
               const float* __restrict__ wo, const float* __restrict__ bo,
               const float* __restrict__ lng, const float* __restrict__ lnb,
               const float* __restrict__ gw, const float* __restrict__ gb,
               const float* __restrict__ pw, const float* __restrict__ pb,
               const float* __restrict__ h1w, const float* __restrict__ h1b,
               const float* __restrict__ h2w, const float* __restrict__ h2b,
               float* __restrict__ out)
{
    __shared__ __attribute__((aligned(16))) float kv_all[WPB * S * ROW];   // 36864 B
    __shared__ __attribute__((aligned(16))) float smc_all[WPB * 192];      //  3072 B

    const int w = threadIdx.x >> 6;          // wave id within block
    const int s = threadIdx.x & 63;          // sequence position (lane)
    const int b = blockIdx.x * WPB + w;      // batch element, one per wave

    float* kv  = &kv_all[w * S * ROW];
    float* smc = &smc_all[w * 192];

    // ---- load x row (coalesced float4 per wave) ----
    const float4 xr = reinterpret_cast<const float4*>(x)[b * S + s];
    float x0[4] = {xr.x, xr.y, xr.z, xr.w};

    // ================= Conv branch (register + shuffle only) =================
    float xm[4], xp[4];
#pragma unroll
    for (int i = 0; i < 4; ++i) {
        float up = __shfl_up(x0[i], 1);
        float dn = __shfl_down(x0[i], 1);
        xm[i] = (s > 0) ? up : 0.f;
        xp[i] = (s < S - 1) ? dn : 0.f;
    }
    float hc[CF];
#pragma unroll
    for (int o = 0; o < CF; ++o) {
        float acc = c1b[o];
#pragma unroll
        for (int i = 0; i < DIN; ++i) {
            acc += xm[i] * c1w[(o * DIN + i) * 3 + 0];
            acc += x0[i] * c1w[(o * DIN + i) * 3 + 1];
            acc += xp[i] * c1w[(o * DIN + i) * 3 + 2];
        }
        hc[o] = fmaxf(acc, 0.f);
    }
    float hm[CF], hp[CF];
#pragma unroll
    for (int o = 0; o < CF; ++o) {
        float up = __shfl_up(hc[o], 1);
        float dn = __shfl_down(hc[o], 1);
        hm[o] = (s > 0) ? up : 0.f;
        hp[o] = (s < S - 1) ? dn : 0.f;
    }
    float h2r[CF];
#pragma unroll
    for (int o = 0; o < CF; ++o) {
        float acc = c2b[o];
#pragma unroll
        for (int i = 0; i < CF; ++i) {
            acc += hm[i] * c2w[(o * CF + i) * 3 + 0];
            acc += hc[i] * c2w[(o * CF + i) * 3 + 1];
            acc += hp[i] * c2w[(o * CF + i) * 3 + 2];
        }
        h2r[o] = fmaxf(acc, 0.f);
    }
    // AdaptiveAvgPool1d over s: full-wave butterfly
#pragma unroll
    for (int o = 0; o < CF; ++o) {
        float v = h2r[o];
#pragma unroll
        for (int off = 32; off > 0; off >>= 1) v += __shfl_xor(v, off);
        h2r[o] = v * (1.f / 64.f);
    }
    if (s < H) {
        float acc = cpb[s];
#pragma unroll
        for (int o = 0; o < CF; ++o) acc += h2r[o] * cpw[s * CF + o];
        smc[s] = acc;   // conv_feat -> smc[0..31]
    }

    // ================= Attention branch =================
    float hr[H];
#pragma unroll
    for (int j = 0; j < H; ++j) {
        hr[j] = ipb[j] + x0[0] * ipw[j * 4 + 0] + x0[1] * ipw[j * 4 + 1]
                       + x0[2] * ipw[j * 4 + 2] + x0[3] * ipw[j * 4 + 3];
    }

    float attn_out[H];
#pragma unroll
    for (int j = 0; j < H; ++j) attn_out[j] = bo[j];

#pragma unroll
    for (int head = 0; head < NHEADS; ++head) {
        // ---- stage k|v rows for this head: row = [k0..k15 | v0..v15 | pad] ----
#pragma unroll
        for (int j4 = 0; j4 < DH / 4; ++j4) {
            float4 kq;
            float* kqf = reinterpret_cast<float*>(&kq);
#pragma unroll
            for (int r = 0; r < 4; ++r) {
                const int j = head * DH + j4 * 4 + r;
                float kk = bk[j];
#pragma unroll
                for (int c = 0; c < H; ++c) kk += hr[c] * wk[j * H + c];
                kqf[r] = kk;
            }
            reinterpret_cast<float4*>(&kv[s * ROW])[j4] = kq;
        }
#pragma unroll
        for (int j4 = 0; j4 < DH / 4; ++j4) {
            float4 vq;
            float* vqf = reinterpret_cast<float*>(&vq);
#pragma unroll
            for (int r = 0; r < 4; ++r) {
                const int j = head * DH + j4 * 4 + r;
                float vv = bv[j];
#pragma unroll
                for (int c = 0; c < H; ++c) vv += hr[c] * wv[j * H + c];
                vqf[r] = vv;
            }
            reinterpret_cast<float4*>(&kv[s * ROW + DH])[j4] = vq;
        }

        // ---- q row (1/sqrt(16) folded); overlaps the LDS-write latency ----
        float qh[DH];
#pragma unroll
        for (int d = 0; d < DH; ++d) {
            const int j = head * DH + d;
            float acc = bq[j];
#pragma unroll
            for (int c = 0; c < H; ++c) acc += hr[c] * wq[j * H + c];
            qh[d] = acc * 0.25f;
        }
        wsync();

        // ---- fused QK -> exp -> PV sweep (no max pass: |score| << 1) ----
        float l = 0.f;
        float ctx[DH];
#pragma unroll
        for (int d = 0; d < DH; ++d) ctx[d] = 0.f;
#pragma unroll 8
        for (int kp = 0; kp < S; ++kp) {
            const float4* r = reinterpret_cast<const float4*>(&kv[kp * ROW]);
            float sa = 0.f, sb = 0.f;     // 2 partial accums: halve the serial chain
            {
                float4 k4 = r[0];
                sa += qh[0] * k4.x + qh[1] * k4.y + qh[2] * k4.z + qh[3] * k4.w;
            }
            {
                float4 k4 = r[2];
                sb += qh[8] * k4.x + qh[9] * k4.y + qh[10] * k4.z + qh[11] * k4.w;
            }
            {
                float4 k4 = r[1];
                sa += qh[4] * k4.x + qh[5] * k4.y + qh[6] * k4.z + qh[7] * k4.w;
            }
            {
                float4 k4 = r[3];
                sb += qh[12] * k4.x + qh[13] * k4.y + qh[14] * k4.z + qh[15] * k4.w;
            }
            const float e = __expf(sa + sb);
            l += e;
#pragma unroll
            for (int dq = 0; dq < 4; ++dq) {
                float4 v4 = r[4 + dq];
                ctx[dq * 4 + 0] += e * v4.x;
                ctx[dq * 4 + 1] += e * v4.y;
                ctx[dq * 4 + 2] += e * v4.z;
                ctx[dq * 4 + 3] += e * v4.w;
            }
        }
        const float inv = 1.f / l;
#pragma unroll
        for (int d = 0; d < DH; ++d) ctx[d] *= inv;

        // attn_out += ctx_head @ wo[:, head*16 : head*16+16].T
#pragma unroll
        for (int j = 0; j < H; ++j) {
            float acc = attn_out[j];
#pragma unroll
            for (int d = 0; d < DH; ++d) acc += ctx[d] * wo[j * H + head * DH + d];
            attn_out[j] = acc;
        }
        wsync();   // wave done reading kv before overwriting next head
    }

    // ---- residual + LayerNorm over H ----
    float y[H];
    float mu = 0.f;
#pragma unroll
    for (int j = 0; j < H; ++j) { y[j] = hr[j] + attn_out[j]; mu += y[j]; }
    mu *= (1.f / 32.f);
    float var = 0.f;
#pragma unroll
    for (int j = 0; j < H; ++j) { float d = y[j] - mu; var += d * d; }
    var *= (1.f / 32.f);
    const float rstd = rsqrtf(var + 1e-5f);
#pragma unroll
    for (int j = 0; j < H; ++j) y[j] = (y[j] - mu) * rstd * lng[j] + lnb[j];

    // ---- att_feat = mean over s: single 32-col pass through kv ----
#pragma unroll
    for (int j4 = 0; j4 < H / 4; ++j4) {
        float4 t;
        t.x = y[j4 * 4 + 0]; t.y = y[j4 * 4 + 1];
        t.z = y[j4 * 4 + 2]; t.w = y[j4 * 4 + 3];
        reinterpret_cast<float4*>(&kv[s * ROW])[j4] = t;
    }
    wsync();
    {
        const int g = s >> 5, j = s & 31;     // two row-groups of 32
        float p = 0.f;
#pragma unroll 8
        for (int r = 0; r < 32; ++r) p += kv[(g * 32 + r) * ROW + j];
        p += __shfl_xor(p, 32);               // combine the two groups
        if (s < H) smc[H + s] = p * (1.f / 64.f);   // att_feat -> smc[32..63]
    }
    wsync();

    // ================= DBMM fusion =================
    {
        const int j = s;   // all 64 lanes
        float acc = gb[j];
        const float4* smc4 = reinterpret_cast<const float4*>(smc);
        const float4* gw4  = reinterpret_cast<const float4*>(&gw[j * 2 * H]);
#pragma unroll
        for (int k4 = 0; k4 < 16; ++k4) {
            float4 cv = smc4[k4];
            float4 wv4 = gw4[k4];
            acc += cv.x * wv4.x + cv.y * wv4.y + cv.z * wv4.z + cv.w * wv4.w;
        }
        const float sig = 1.f / (1.f + __expf(-acc));
        smc[64 + j] = smc[j] * sig;        // gated
    }
    wsync();
    if (s < H) {
        float acc = pb[s];
        const float4* smc4 = reinterpret_cast<const float4*>(smc + 64);
        const float4* pw4  = reinterpret_cast<const float4*>(&pw[s * 2 * H]);
#pragma unroll
        for (int k4 = 0; k4 < 16; ++k4) {
            float4 cv = smc4[k4];
            float4 wv4 = pw4[k4];
            acc += cv.x * wv4.x + cv.y * wv4.y + cv.z * wv4.z + cv.w * wv4.w;
        }
        smc[128 + s] = acc;                // fused
    }
    wsync();

    // ================= Output head =================
    if (s < 16) {
        float acc = h1b[s];
#pragma unroll
        for (int c = 0; c < H; ++c) acc += smc[128 + c] * h1w[s * H + c];
        smc[160 + s] = fmaxf(acc, 0.f);    // t1
    }
    wsync();
    if (s < 2) {
        float acc = h2b[s];
#pragma unroll
        for (int c = 0; c < 16; ++c) acc += smc[160 + c] * h2w[s * 16 + c];
        out[b * 2 + s] = acc;
    }
}

extern "C" void kernel_launch(void* const* d_in, const int* in_sizes, int n_in,
                              void* d_out, int out_size, void* d_ws, size_t ws_size,
                              hipStream_t stream) {
    (void)n_in; (void)d_ws; (void)ws_size;
    const int nb = out_size / 2;   // B
    const float* xp_ = (const float*)d_in[0];
    const float* c1w = (const float*)d_in[1];  const float* c1b = (const float*)d_in[2];
    const float* c2w = (const float*)d_in[3];  const float* c2b = (const float*)d_in[4];
    const float* cpw = (const float*)d_in[5];  const float* cpb = (const float*)d_in[6];
    const float* ipw = (const float*)d_in[7];  const float* ipb = (const float*)d_in[8];
    const float* wq  = (const float*)d_in[9];  const float* bq  = (const float*)d_in[10];
    const float* wk  = (const float*)d_in[11]; const float* bk  = (const float*)d_in[12];
    const float* wv  = (const float*)d_in[13]; const float* bv  = (const float*)d_in[14];
    const float* wo  = (const float*)d_in[15]; const float* bo  = (const float*)d_in[16];
    const float* lng = (const float*)d_in[17]; const float* lnb = (const float*)d_in[18];
    const float* gw  = (const float*)d_in[19]; const float* gb  = (const float*)d_in[20];
    const float* pw  = (const float*)d_in[21]; const float* pb  = (const float*)d_in[22];
    const float* h1w = (const float*)d_in[23]; const float* h1b = (const float*)d_in[24];
    const float* h2w = (const float*)d_in[25]; const float* h2b = (const float*)d_in[26];
    float* outp = (float*)d_out;

    dim3 grid(nb / WPB), block(WPB * 64);
    hipLaunchKernelGGL(fused_fwd, grid, block, 0, stream,
                       xp_, c1w, c1b, c2w, c2b, cpw, cpb, ipw, ipb,
                       wq, bq, wk, bk, wv, bv, wo, bo, lng, lnb,
                       gw, gb, pw, pb, h1w, h1b, h2w, h2b, outp);
}

// Round 6
// 298.094 us; speedup vs baseline: 2.6677x; 2.4021x over previous
//
#include <hip/hip_runtime.h>
#include <math.h>

#define S 64
#define DIN 4
#define H 32
#define CF 16
#define DH 16
#define WPB 4

typedef __attribute__((ext_vector_type(8))) short bf16x8;
typedef __attribute__((ext_vector_type(4))) short s16x4;
typedef __attribute__((ext_vector_type(4))) float f32x4;

#define MFMA(a, b, c) __builtin_amdgcn_mfma_f32_16x16x32_bf16((a), (b), (c), 0, 0, 0)

// Wave-local fence: compiler ordering only; LDS ops of one wave complete in order.
__device__ __forceinline__ void wsync() {
    asm volatile("" ::: "memory");
    __builtin_amdgcn_wave_barrier();
    asm volatile("" ::: "memory");
}

__device__ __forceinline__ short f2bf(float f) {   // RNE f32 -> bf16 bits
    union { float f; unsigned u; } v; v.f = f;
    unsigned r = (v.u + 0x7FFFu + ((v.u >> 16) & 1u)) >> 16;
    return (short)r;
}

__device__ __forceinline__ bf16x8 frag8(const float* p) {  // 8 consecutive f32 -> bf16x8
    f32x4 a = *(const f32x4*)p;
    f32x4 b = *(const f32x4*)(p + 4);
    bf16x8 f;
    f[0] = f2bf(a[0]); f[1] = f2bf(a[1]); f[2] = f2bf(a[2]); f[3] = f2bf(a[3]);
    f[4] = f2bf(b[0]); f[5] = f2bf(b[1]); f[6] = f2bf(b[2]); f[7] = f2bf(b[3]);
    return f;
}

__device__ __forceinline__ s16x4 pack4(float a, float b, float c, float d) {
    s16x4 v; v[0] = f2bf(a); v[1] = f2bf(b); v[2] = f2bf(c); v[3] = f2bf(d); return v;
}

// MFMA conventions used (verified basis: m89/m91 C/D layout; operand rows = lane&15;
// A/B k-slot symmetry — same basis as the swapped-QK trick):
//   D = arg0 * arg1^T ; both args: row = lane&15 (+16*tile), k-slot = ((lane>>4), elem)
//   D tile: col = lane&15 (arg1 row), row = (lane>>4)*4 + reg (arg0 row)

__global__ __launch_bounds__(WPB * 64, 2)
void fused_fwd(const float* __restrict__ x,
               const float* __restrict__ c1w, const float* __restrict__ c1b,
               const float* __restrict__ c2w, const float* __restrict__ c2b,
               const float* __restrict__ cpw, const float* __restrict__ cpb,
               const float* __restrict__ ipw, const float* __restrict__ ipb,
               const float* __restrict__ wq, const float* __restrict__ bq,
               const float* __restrict__ wk, const float* __restrict__ bk,
               const float* __restrict__ wv, const float* __restrict__ bv,
               const float* __restrict__ wo, const float* __restrict__ bo,
               const float* __restrict__ lng, const float* __restrict__ lnb,
               const float* __restrict__ gw, const float* __restrict__ gb,
               const float* __restrict__ pw, const float* __restrict__ pb,
               const float* __restrict__ h1w, const float* __restrict__ h1b,
               const float* __restrict__ h2w, const float* __restrict__ h2b,
               float* __restrict__ out)
{
    // per-wave arenas (one wave = one sample)
    __shared__ __attribute__((aligned(16))) float hA_all[WPB * S * 36];   // h fp32 [64][36]
    __shared__ __attribute__((aligned(16))) short R_all[WPB * S * 48];    // qk[64][48] -> pt[64][40] -> ctx[64][40]
    __shared__ __attribute__((aligned(16))) short Vt_all[WPB * 16 * 72];  // V^T [16][72]
    __shared__ __attribute__((aligned(16))) float smc_all[WPB * 192];

    const int w  = threadIdx.x >> 6;
    const int s  = threadIdx.x & 63;     // lane = seq position / worker id
    const int fr = s & 15;
    const int g  = s >> 4;
    const int b  = blockIdx.x * WPB + w;

    float* hA  = hA_all  + w * (S * 36);
    short* R   = R_all   + w * (S * 48);
    short* Vt  = Vt_all  + w * (16 * 72);
    float* smc = smc_all + w * 192;

    // ---- load x row ----
    const f32x4 xr = reinterpret_cast<const f32x4*>(x)[b * S + s];
    float x0[4] = {xr[0], xr[1], xr[2], xr[3]};

    // ================= Conv branch (VALU + shuffle, unchanged) =================
    float xm[4], xp[4];
#pragma unroll
    for (int i = 0; i < 4; ++i) {
        float up = __shfl_up(x0[i], 1);
        float dn = __shfl_down(x0[i], 1);
        xm[i] = (s > 0) ? up : 0.f;
        xp[i] = (s < S - 1) ? dn : 0.f;
    }
    float hc[CF];
#pragma unroll
    for (int o = 0; o < CF; ++o) {
        float acc = c1b[o];
#pragma unroll
        for (int i = 0; i < DIN; ++i) {
            acc += xm[i] * c1w[(o * DIN + i) * 3 + 0];
            acc += x0[i] * c1w[(o * DIN + i) * 3 + 1];
            acc += xp[i] * c1w[(o * DIN + i) * 3 + 2];
        }
        hc[o] = fmaxf(acc, 0.f);
    }
    float hm[CF], hp[CF];
#pragma unroll
    for (int o = 0; o < CF; ++o) {
        float up = __shfl_up(hc[o], 1);
        float dn = __shfl_down(hc[o], 1);
        hm[o] = (s > 0) ? up : 0.f;
        hp[o] = (s < S - 1) ? dn : 0.f;
    }
    float h2r[CF];
#pragma unroll
    for (int o = 0; o < CF; ++o) {
        float acc = c2b[o];
#pragma unroll
        for (int i = 0; i < CF; ++i) {
            acc += hm[i] * c2w[(o * CF + i) * 3 + 0];
            acc += hc[i] * c2w[(o * CF + i) * 3 + 1];
            acc += hp[i] * c2w[(o * CF + i) * 3 + 2];
        }
        h2r[o] = fmaxf(acc, 0.f);
    }
#pragma unroll
    for (int o = 0; o < CF; ++o) {
        float v = h2r[o];
#pragma unroll
        for (int off = 32; off > 0; off >>= 1) v += __shfl_xor(v, off);
        h2r[o] = v * (1.f / 64.f);
    }
    if (s < H) {
        float acc = cpb[s];
#pragma unroll
        for (int o = 0; o < CF; ++o) acc += h2r[o] * cpw[s * CF + o];
        smc[s] = acc;   // conv_feat -> smc[0..31]
    }

    // ================= h projection (fp32) -> hA =================
    {
        float hr[H];
#pragma unroll
        for (int j = 0; j < H; ++j) {
            hr[j] = ipb[j] + x0[0] * ipw[j * 4 + 0] + x0[1] * ipw[j * 4 + 1]
                           + x0[2] * ipw[j * 4 + 2] + x0[3] * ipw[j * 4 + 3];
        }
#pragma unroll
        for (int i = 0; i < 8; ++i) {
            f32x4 t = {hr[4 * i], hr[4 * i + 1], hr[4 * i + 2], hr[4 * i + 3]};
            *(f32x4*)&hA[s * 36 + 4 * i] = t;
        }
    }
    wsync();

    const bf16x8 z8 = {0, 0, 0, 0, 0, 0, 0, 0};
    const f32x4  z4 = {0.f, 0.f, 0.f, 0.f};

    // y accumulator in D-layout: j = mt*16 + g*4 + reg, sq = nt*16 + fr
    f32x4 yD[2][4];
#pragma unroll
    for (int mt = 0; mt < 2; ++mt) {
        f32x4 bo4 = *(const f32x4*)&bo[mt * 16 + g * 4];
#pragma unroll
        for (int nt = 0; nt < 4; ++nt) yD[mt][nt] = bo4;
    }

#pragma unroll
    for (int h = 0; h < 2; ++h) {
        // ---- h fragments (rows s, slots c) ----
        bf16x8 hF[4];
#pragma unroll
        for (int t = 0; t < 4; ++t) hF[t] = frag8(&hA[(t * 16 + fr) * 36 + g * 8]);

        // ---- weight fragments from global (rows j of head h, slots c full K=32) ----
        bf16x8 wqF = frag8(&wq[(h * 16 + fr) * 32 + g * 8]);
        bf16x8 wkF = frag8(&wk[(h * 16 + fr) * 32 + g * 8]);
        bf16x8 wvF = frag8(&wv[(h * 16 + fr) * 32 + g * 8]);
        f32x4 bq4 = *(const f32x4*)&bq[h * 16 + g * 4];
        f32x4 bk4 = *(const f32x4*)&bk[h * 16 + g * 4];
        float bvv = bv[h * 16 + fr];

        // ---- q,k projections: D[j_local][s] = W . h^T + bias; pack b64 into qk rows ----
#pragma unroll
        for (int nt = 0; nt < 4; ++nt) {
            f32x4 aq = MFMA(wqF, hF[nt], bq4);
            *(s16x4*)&R[(nt * 16 + fr) * 48 + g * 4] =
                pack4(aq[0] * 0.25f, aq[1] * 0.25f, aq[2] * 0.25f, aq[3] * 0.25f);
            f32x4 ak = MFMA(wkF, hF[nt], bk4);
            *(s16x4*)&R[(nt * 16 + fr) * 48 + 16 + g * 4] =
                pack4(ak[0], ak[1], ak[2], ak[3]);
        }
        // ---- v projection: D[s_local][d] = h . Wv^T + bv; pack b64 into Vt[d][s] ----
#pragma unroll
        for (int mi = 0; mi < 4; ++mi) {
            f32x4 cv = {bvv, bvv, bvv, bvv};
            f32x4 av = MFMA(hF[mi], wvF, cv);
            *(s16x4*)&Vt[fr * 72 + mi * 16 + g * 4] = pack4(av[0], av[1], av[2], av[3]);
        }
        wsync();

        // ---- scores: P^T = K . Q^T (K-dim 16, zero-masked lane-groups g>=2) ----
        bf16x8 qF[4], kF[4];
#pragma unroll
        for (int t = 0; t < 4; ++t) {
            bf16x8 fq = z8, fk = z8;
            if (g < 2) {
                fq = *(const bf16x8*)&R[(t * 16 + fr) * 48 + g * 8];
                fk = *(const bf16x8*)&R[(t * 16 + fr) * 48 + 16 + g * 8];
            }
            qF[t] = fq; kF[t] = fk;
        }
        f32x4 pA[4][4];   // pA[mi][nj]: sk = mi*16+g*4+reg, sq = nj*16+fr
#pragma unroll
        for (int mi = 0; mi < 4; ++mi)
#pragma unroll
            for (int nj = 0; nj < 4; ++nj)
                pA[mi][nj] = MFMA(kF[mi], qF[nj], z4);

        // ---- softmax (no max-subtraction: |score| << 1), denom = col-sum of P^T ----
        float inv[4];
#pragma unroll
        for (int nj = 0; nj < 4; ++nj) {
            float l = 0.f;
#pragma unroll
            for (int mi = 0; mi < 4; ++mi)
#pragma unroll
                for (int r = 0; r < 4; ++r) {
                    float e = __expf(pA[mi][nj][r]);
                    pA[mi][nj][r] = e;
                    l += e;
                }
            l += __shfl_xor(l, 16);
            l += __shfl_xor(l, 32);
            inv[nj] = 1.0f / l;
        }

        // ---- PV: ctx^T = V^T . P̂^T, K=64 in two half passes through R ----
        f32x4 cAcc[4] = {z4, z4, z4, z4};
#pragma unroll
        for (int kk = 0; kk < 2; ++kk) {
            wsync();   // prior readers of R done
#pragma unroll
            for (int m2 = 0; m2 < 2; ++m2) {
                const int mi = kk * 2 + m2;
#pragma unroll
                for (int nj = 0; nj < 4; ++nj)
                    *(s16x4*)&R[(nj * 16 + fr) * 40 + m2 * 16 + g * 4] =
                        pack4(pA[mi][nj][0] * inv[nj], pA[mi][nj][1] * inv[nj],
                              pA[mi][nj][2] * inv[nj], pA[mi][nj][3] * inv[nj]);
            }
            wsync();
            bf16x8 vtF = *(const bf16x8*)&Vt[fr * 72 + kk * 32 + g * 8];
#pragma unroll
            for (int nt = 0; nt < 4; ++nt) {
                bf16x8 ptF = *(const bf16x8*)&R[(nt * 16 + fr) * 40 + g * 8];
                cAcc[nt] = MFMA(vtF, ptF, cAcc[nt]);
            }
        }
        wsync();

        // ---- ctx to LDS row-major [sq][d] (b64 packed) ----
#pragma unroll
        for (int nt = 0; nt < 4; ++nt)
            *(s16x4*)&R[(nt * 16 + fr) * 40 + g * 4] =
                pack4(cAcc[nt][0], cAcc[nt][1], cAcc[nt][2], cAcc[nt][3]);
        wsync();

        // ---- wo: yD += Wo[:, h-slice] . ctx^T (accumulates across heads) ----
        bf16x8 woF[2];
#pragma unroll
        for (int mt = 0; mt < 2; ++mt) {
            bf16x8 f = frag8(&wo[(mt * 16 + fr) * 32 + h * 16 + (g & 1) * 8]);
            if (g >= 2) f = z8;
            woF[mt] = f;
        }
#pragma unroll
        for (int nt = 0; nt < 4; ++nt) {
            bf16x8 cF = *(const bf16x8*)&R[(nt * 16 + fr) * 40 + g * 8];
#pragma unroll
            for (int mt = 0; mt < 2; ++mt)
                yD[mt][nt] = MFMA(woF[mt], cF, yD[mt][nt]);
        }
        wsync();   // before next head overwrites R / Vt
    }

    // ================= residual + LayerNorm in D-layout =================
#pragma unroll
    for (int mt = 0; mt < 2; ++mt)
#pragma unroll
        for (int nt = 0; nt < 4; ++nt) {
            f32x4 hh = *(const f32x4*)&hA[(nt * 16 + fr) * 36 + mt * 16 + g * 4];
#pragma unroll
            for (int r = 0; r < 4; ++r) yD[mt][nt][r] += hh[r];
        }
    f32x4 lg0 = *(const f32x4*)&lng[g * 4];
    f32x4 lg1 = *(const f32x4*)&lng[16 + g * 4];
    f32x4 lb0 = *(const f32x4*)&lnb[g * 4];
    f32x4 lb1 = *(const f32x4*)&lnb[16 + g * 4];
#pragma unroll
    for (int nt = 0; nt < 4; ++nt) {
        float sy = 0.f, sy2 = 0.f;
#pragma unroll
        for (int mt = 0; mt < 2; ++mt)
#pragma unroll
            for (int r = 0; r < 4; ++r) {
                float v = yD[mt][nt][r];
                sy += v; sy2 += v * v;
            }
        sy  += __shfl_xor(sy, 16);  sy  += __shfl_xor(sy, 32);
        sy2 += __shfl_xor(sy2, 16); sy2 += __shfl_xor(sy2, 32);
        const float mu   = sy * (1.f / 32.f);
        const float var  = sy2 * (1.f / 32.f) - mu * mu;
        const float rstd = rsqrtf(var + 1e-5f);
#pragma unroll
        for (int r = 0; r < 4; ++r) {
            yD[0][nt][r] = (yD[0][nt][r] - mu) * rstd * lg0[r] + lb0[r];
            yD[1][nt][r] = (yD[1][nt][r] - mu) * rstd * lg1[r] + lb1[r];
        }
    }

    // ---- att_feat = mean over sq ----
#pragma unroll
    for (int mt = 0; mt < 2; ++mt)
#pragma unroll
        for (int r = 0; r < 4; ++r) {
            float af = yD[mt][0][r] + yD[mt][1][r] + yD[mt][2][r] + yD[mt][3][r];
            af += __shfl_xor(af, 1);
            af += __shfl_xor(af, 2);
            af += __shfl_xor(af, 4);
            af += __shfl_xor(af, 8);
            if (fr == 0) smc[H + mt * 16 + g * 4 + r] = af * (1.f / 64.f);
        }
    wsync();

    // ================= DBMM fusion =================
    {
        const int j = s;
        float acc = gb[j];
        const f32x4* smc4 = (const f32x4*)smc;
        const f32x4* gw4  = (const f32x4*)&gw[j * 2 * H];
#pragma unroll
        for (int k4 = 0; k4 < 16; ++k4) {
            f32x4 cv = smc4[k4], wv4 = gw4[k4];
            acc += cv[0] * wv4[0] + cv[1] * wv4[1] + cv[2] * wv4[2] + cv[3] * wv4[3];
        }
        const float sig = 1.f / (1.f + __expf(-acc));
        smc[64 + j] = smc[j] * sig;
    }
    wsync();
    if (s < H) {
        float acc = pb[s];
        const f32x4* smc4 = (const f32x4*)(smc + 64);
        const f32x4* pw4  = (const f32x4*)&pw[s * 2 * H];
#pragma unroll
        for (int k4 = 0; k4 < 16; ++k4) {
            f32x4 cv = smc4[k4], wv4 = pw4[k4];
            acc += cv[0] * wv4[0] + cv[1] * wv4[1] + cv[2] * wv4[2] + cv[3] * wv4[3];
        }
        smc[128 + s] = acc;
    }
    wsync();
    if (s < 16) {
        float acc = h1b[s];
#pragma unroll
        for (int c = 0; c < H; ++c) acc += smc[128 + c] * h1w[s * H + c];
        smc[160 + s] = fmaxf(acc, 0.f);
    }
    wsync();
    if (s < 2) {
        float acc = h2b[s];
#pragma unroll
        for (int c = 0; c < 16; ++c) acc += smc[160 + c] * h2w[s * 16 + c];
        out[b * 2 + s] = acc;
    }
}

extern "C" void kernel_launch(void* const* d_in, const int* in_sizes, int n_in,
                              void* d_out, int out_size, void* d_ws, size_t ws_size,
                              hipStream_t stream) {
    (void)n_in; (void)d_ws; (void)ws_size; (void)in_sizes;
    const int nb = out_size / 2;   // B
    const float* xp_ = (const float*)d_in[0];
    const float* c1w = (const float*)d_in[1];  const float* c1b = (const float*)d_in[2];
    const float* c2w = (const float*)d_in[3];  const float* c2b = (const float*)d_in[4];
    const float* cpw = (const float*)d_in[5];  const float* cpb = (const float*)d_in[6];
    const float* ipw = (const float*)d_in[7];  const float* ipb = (const float*)d_in[8];
    const float* wq  = (const float*)d_in[9];  const float* bq  = (const float*)d_in[10];
    const float* wk  = (const float*)d_in[11]; const float* bk  = (const float*)d_in[12];
    const float* wv  = (const float*)d_in[13]; const float* bv  = (const float*)d_in[14];
    const float* wo  = (const float*)d_in[15]; const float* bo  = (const float*)d_in[16];
    const float* lng = (const float*)d_in[17]; const float* lnb = (const float*)d_in[18];
    const float* gw  = (const float*)d_in[19]; const float* gb  = (const float*)d_in[20];
    const float* pw  = (const float*)d_in[21]; const float* pb  = (const float*)d_in[22];
    const float* h1w = (const float*)d_in[23]; const float* h1b = (const float*)d_in[24];
    const float* h2w = (const float*)d_in[25]; const float* h2b = (const float*)d_in[26];
    float* outp = (float*)d_out;

    dim3 grid(nb / WPB), block(WPB * 64);
    hipLaunchKernelGGL(fused_fwd, grid, block, 0, stream,
                       xp_, c1w, c1b, c2w, c2b, cpw, cpb, ipw, ipb,
                       wq, bq, wk, bk, wv, bv, wo, bo, lng, lnb,
                       gw, gb, pw, pb, h1w, h1b, h2w, h2b, outp);
}

// Round 7
// 248.746 us; speedup vs baseline: 3.1969x; 1.1984x over previous
//
#include <hip/hip_runtime.h>
#include <hip/hip_bf16.h>
#include <math.h>

#define S 64
#define DIN 4
#define H 32
#define CF 16
#define WPB 4

typedef __attribute__((ext_vector_type(8))) short bf16x8;
typedef __attribute__((ext_vector_type(4))) short s16x4;
typedef __attribute__((ext_vector_type(4))) float f32x4;

#define MFMA(a, b, c) __builtin_amdgcn_mfma_f32_16x16x32_bf16((a), (b), (c), 0, 0, 0)

// Wave-local fence: compiler ordering only; one wave's LDS ops to its private
// arena complete in order (validated R5/R6).
__device__ __forceinline__ void wsync() {
    asm volatile("" ::: "memory");
    __builtin_amdgcn_wave_barrier();
    asm volatile("" ::: "memory");
}

__device__ __forceinline__ short f2bf(float f) {   // RNE via compiler-best cast
    __hip_bfloat16 h = __float2bfloat16(f);
    return *reinterpret_cast<short*>(&h);
}

__device__ __forceinline__ bf16x8 frag8(const float* p) {  // 8 f32 -> bf16x8
    f32x4 a = *(const f32x4*)p;
    f32x4 b = *(const f32x4*)(p + 4);
    bf16x8 f;
    f[0] = f2bf(a[0]); f[1] = f2bf(a[1]); f[2] = f2bf(a[2]); f[3] = f2bf(a[3]);
    f[4] = f2bf(b[0]); f[5] = f2bf(b[1]); f[6] = f2bf(b[2]); f[7] = f2bf(b[3]);
    return f;
}

__device__ __forceinline__ s16x4 pack4(float a, float b, float c, float d) {
    s16x4 v; v[0] = f2bf(a); v[1] = f2bf(b); v[2] = f2bf(c); v[3] = f2bf(d); return v;
}

// MFMA conventions (verified in R6, basis m89/m91):
//   D = arg0 * arg1^T ; args: row = lane&15 (+16*tile), k-slot = (lane>>4, elem)
//   D tile: col = lane&15 (arg1 row), row = (lane>>4)*4 + reg (arg0 row)

__global__ __launch_bounds__(WPB * 64, 2)
void fused_fwd(const float* __restrict__ x,
               const float* __restrict__ c1w, const float* __restrict__ c1b,
               const float* __restrict__ c2w, const float* __restrict__ c2b,
               const float* __restrict__ cpw, const float* __restrict__ cpb,
               const float* __restrict__ ipw, const float* __restrict__ ipb,
               const float* __restrict__ wq, const float* __restrict__ bq,
               const float* __restrict__ wk, const float* __restrict__ bk,
               const float* __restrict__ wv, const float* __restrict__ bv,
               const float* __restrict__ wo, const float* __restrict__ bo,
               const float* __restrict__ lng, const float* __restrict__ lnb,
               const float* __restrict__ gw, const float* __restrict__ gb,
               const float* __restrict__ pw, const float* __restrict__ pb,
               const float* __restrict__ h1w, const float* __restrict__ h1b,
               const float* __restrict__ h2w, const float* __restrict__ h2b,
               float* __restrict__ out)
{
    // Two per-wave arenas, 5120 B each -> 10240 B/wave, 40960 B/block = 4 blk/CU.
    // R: qk (q cols 0-15, k cols 24-39) -> P̂ (cols 0-31) -> ctx (cols 0-15), stride 40.
    // U: hB bf16 [64][40] (pre-loop) -> { Vt [16][72] | smc (f32[192] @ +1152) }.
    __shared__ __attribute__((aligned(16))) short R_all[WPB * 2560];
    __shared__ __attribute__((aligned(16))) short U_all[WPB * 2560];

    const int w  = threadIdx.x >> 6;
    const int s  = threadIdx.x & 63;
    const int fr = s & 15;
    const int g  = s >> 4;
    const int b  = blockIdx.x * WPB + w;

    short* R   = R_all + w * 2560;
    short* U   = U_all + w * 2560;
    short* hB  = U;                                    // pre-loop life
    short* Vt  = U;                                    // head-loop life (cols 0..1151)
    float* smc = reinterpret_cast<float*>(U + 1152);   // life starts after hB dies

    // ---- load x row ----
    const f32x4 xr = reinterpret_cast<const f32x4*>(x)[b * S + s];
    float x0[4] = {xr[0], xr[1], xr[2], xr[3]};

    // ================= Conv branch (VALU + shuffle) =================
    float xm[4], xp[4];
#pragma unroll
    for (int i = 0; i < 4; ++i) {
        float up = __shfl_up(x0[i], 1);
        float dn = __shfl_down(x0[i], 1);
        xm[i] = (s > 0) ? up : 0.f;
        xp[i] = (s < S - 1) ? dn : 0.f;
    }
    float hc[CF];
#pragma unroll
    for (int o = 0; o < CF; ++o) {
        float acc = c1b[o];
#pragma unroll
        for (int i = 0; i < DIN; ++i) {
            acc += xm[i] * c1w[(o * DIN + i) * 3 + 0];
            acc += x0[i] * c1w[(o * DIN + i) * 3 + 1];
            acc += xp[i] * c1w[(o * DIN + i) * 3 + 2];
        }
        hc[o] = fmaxf(acc, 0.f);
    }
    float hm[CF], hp[CF];
#pragma unroll
    for (int o = 0; o < CF; ++o) {
        float up = __shfl_up(hc[o], 1);
        float dn = __shfl_down(hc[o], 1);
        hm[o] = (s > 0) ? up : 0.f;
        hp[o] = (s < S - 1) ? dn : 0.f;
    }
    float h2r[CF];
#pragma unroll
    for (int o = 0; o < CF; ++o) {
        float acc = c2b[o];
#pragma unroll
        for (int i = 0; i < CF; ++i) {
            acc += hm[i] * c2w[(o * CF + i) * 3 + 0];
            acc += hc[i] * c2w[(o * CF + i) * 3 + 1];
            acc += hp[i] * c2w[(o * CF + i) * 3 + 2];
        }
        h2r[o] = fmaxf(acc, 0.f);
    }
#pragma unroll
    for (int o = 0; o < CF; ++o) {
        float v = h2r[o];
#pragma unroll
        for (int off = 32; off > 0; off >>= 1) v += __shfl_xor(v, off);
        h2r[o] = v * (1.f / 64.f);
    }
    float convf = 0.f;           // conv_feat held in reg until hB arena is dead
    if (s < H) {
        float acc = cpb[s];
#pragma unroll
        for (int o = 0; o < CF; ++o) acc += h2r[o] * cpw[s * CF + o];
        convf = acc;
    }

    // ================= h projection -> bf16 LDS [64][40] =================
    {
        float hr[H];
#pragma unroll
        for (int j = 0; j < H; ++j) {
            hr[j] = ipb[j] + x0[0] * ipw[j * 4 + 0] + x0[1] * ipw[j * 4 + 1]
                           + x0[2] * ipw[j * 4 + 2] + x0[3] * ipw[j * 4 + 3];
        }
#pragma unroll
        for (int i = 0; i < 4; ++i) {
            bf16x8 t;
#pragma unroll
            for (int e = 0; e < 8; ++e) t[e] = f2bf(hr[i * 8 + e]);
            *(bf16x8*)&hB[s * 40 + i * 8] = t;
        }
    }
    wsync();

    // h fragments, computed ONCE (rows t*16+fr, k-slots g*8..g*8+7; full K=32)
    bf16x8 hF[4];
#pragma unroll
    for (int t = 0; t < 4; ++t) hF[t] = *(const bf16x8*)&hB[(t * 16 + fr) * 40 + g * 8];
    // hB is now dead -> smc region of U becomes valid
    if (s < H) smc[s] = convf;   // conv_feat -> smc[0..31]
    wsync();

    const bf16x8 z8 = {0, 0, 0, 0, 0, 0, 0, 0};
    const f32x4  z4 = {0.f, 0.f, 0.f, 0.f};

    // y accumulator in D-layout: j = mt*16 + g*4 + reg, sq = nt*16 + fr
    f32x4 yD[2][4];
#pragma unroll
    for (int mt = 0; mt < 2; ++mt) {
        f32x4 bo4 = *(const f32x4*)&bo[mt * 16 + g * 4];
#pragma unroll
        for (int nt = 0; nt < 4; ++nt) yD[mt][nt] = bo4;
    }

#pragma unroll
    for (int h = 0; h < 2; ++h) {
        // ---- weight fragments (rows fr of head h, full K=32 slots) ----
        bf16x8 wqF = frag8(&wq[(h * 16 + fr) * 32 + g * 8]);
        bf16x8 wkF = frag8(&wk[(h * 16 + fr) * 32 + g * 8]);
        bf16x8 wvF = frag8(&wv[(h * 16 + fr) * 32 + g * 8]);
        f32x4 bq4 = *(const f32x4*)&bq[h * 16 + g * 4];
        f32x4 bk4 = *(const f32x4*)&bk[h * 16 + g * 4];
        float bvv = bv[h * 16 + fr];

        // ---- q,k projections: D[j_local][sq]; q -> cols 0-15, k -> cols 24-39 ----
#pragma unroll
        for (int nt = 0; nt < 4; ++nt) {
            f32x4 aq = MFMA(wqF, hF[nt], bq4);
            *(s16x4*)&R[(nt * 16 + fr) * 40 + g * 4] =
                pack4(aq[0] * 0.25f, aq[1] * 0.25f, aq[2] * 0.25f, aq[3] * 0.25f);
            f32x4 ak = MFMA(wkF, hF[nt], bk4);
            *(s16x4*)&R[(nt * 16 + fr) * 40 + 24 + g * 4] =
                pack4(ak[0], ak[1], ak[2], ak[3]);
        }
        // ---- v projection: D[sq_local][d] -> Vt[d][sq] ----
#pragma unroll
        for (int mi = 0; mi < 4; ++mi) {
            f32x4 cv = {bvv, bvv, bvv, bvv};
            f32x4 av = MFMA(hF[mi], wvF, cv);
            *(s16x4*)&Vt[fr * 72 + mi * 16 + g * 4] = pack4(av[0], av[1], av[2], av[3]);
        }
        wsync();

        // ---- scores: P^T = K . Q^T (K-dim 16, lane-groups g>=2 zero-masked) ----
        bf16x8 qF[4], kF[4];
#pragma unroll
        for (int t = 0; t < 4; ++t) {
            bf16x8 fq = z8, fk = z8;
            if (g < 2) {
                fq = *(const bf16x8*)&R[(t * 16 + fr) * 40 + g * 8];
                fk = *(const bf16x8*)&R[(t * 16 + fr) * 40 + 24 + g * 8];
            }
            qF[t] = fq; kF[t] = fk;
        }
        f32x4 pA[4][4];   // pA[mi][nj]: sk = mi*16+g*4+reg, sq = nj*16+fr
#pragma unroll
        for (int mi = 0; mi < 4; ++mi)
#pragma unroll
            for (int nj = 0; nj < 4; ++nj)
                pA[mi][nj] = MFMA(kF[mi], qF[nj], z4);

        // ---- softmax denom (no max pass: |score| << 1); P̂ left unnormalized ----
        float inv[4];
#pragma unroll
        for (int nj = 0; nj < 4; ++nj) {
            float l = 0.f;
#pragma unroll
            for (int mi = 0; mi < 4; ++mi)
#pragma unroll
                for (int r = 0; r < 4; ++r) {
                    float e = __expf(pA[mi][nj][r]);
                    pA[mi][nj][r] = e;
                    l += e;
                }
            l += __shfl_xor(l, 16);
            l += __shfl_xor(l, 32);
            inv[nj] = 1.0f / l;
        }

        // ---- PV: ctx^T = V^T . P̂^T, K=64 in two half passes through R ----
        f32x4 cAcc[4] = {z4, z4, z4, z4};
#pragma unroll
        for (int kk = 0; kk < 2; ++kk) {
            wsync();   // prior R readers done
#pragma unroll
            for (int m2 = 0; m2 < 2; ++m2) {
                const int mi = kk * 2 + m2;
#pragma unroll
                for (int nj = 0; nj < 4; ++nj)
                    *(s16x4*)&R[(nj * 16 + fr) * 40 + m2 * 16 + g * 4] =
                        pack4(pA[mi][nj][0], pA[mi][nj][1],
                              pA[mi][nj][2], pA[mi][nj][3]);
            }
            wsync();
            bf16x8 vtF = *(const bf16x8*)&Vt[fr * 72 + kk * 32 + g * 8];
#pragma unroll
            for (int nt = 0; nt < 4; ++nt) {
                bf16x8 ptF = *(const bf16x8*)&R[(nt * 16 + fr) * 40 + g * 8];
                cAcc[nt] = MFMA(vtF, ptF, cAcc[nt]);
            }
        }
        // fold softmax normalization here (col sq = nt*16+fr -> inv[nt])
#pragma unroll
        for (int nt = 0; nt < 4; ++nt)
#pragma unroll
            for (int r = 0; r < 4; ++r) cAcc[nt][r] *= inv[nt];
        wsync();

        // ---- ctx to LDS row-major [sq][d] ----
#pragma unroll
        for (int nt = 0; nt < 4; ++nt)
            *(s16x4*)&R[(nt * 16 + fr) * 40 + g * 4] =
                pack4(cAcc[nt][0], cAcc[nt][1], cAcc[nt][2], cAcc[nt][3]);
        wsync();

        // ---- wo: yD += Wo[:, h-slice] . ctx^T ----
        bf16x8 woF[2];
#pragma unroll
        for (int mt = 0; mt < 2; ++mt) {
            bf16x8 f = frag8(&wo[(mt * 16 + fr) * 32 + h * 16 + (g & 1) * 8]);
            if (g >= 2) f = z8;
            woF[mt] = f;
        }
#pragma unroll
        for (int nt = 0; nt < 4; ++nt) {
            bf16x8 cF = z8;
            if (g < 2) cF = *(const bf16x8*)&R[(nt * 16 + fr) * 40 + g * 8];
#pragma unroll
            for (int mt = 0; mt < 2; ++mt)
                yD[mt][nt] = MFMA(woF[mt], cF, yD[mt][nt]);
        }
        wsync();   // before next head overwrites R / Vt
    }

    // ================= residual (recomputed fp32 from x) + LayerNorm =================
    {
        f32x4 xq[4];
#pragma unroll
        for (int nt = 0; nt < 4; ++nt)
            xq[nt] = reinterpret_cast<const f32x4*>(x)[b * S + nt * 16 + fr];
#pragma unroll
        for (int mt = 0; mt < 2; ++mt)
#pragma unroll
            for (int r = 0; r < 4; ++r) {
                const int j = mt * 16 + g * 4 + r;
                const f32x4 wr4 = *(const f32x4*)&ipw[j * 4];
                const float bb = ipb[j];
#pragma unroll
                for (int nt = 0; nt < 4; ++nt)
                    yD[mt][nt][r] += bb + xq[nt][0] * wr4[0] + xq[nt][1] * wr4[1]
                                        + xq[nt][2] * wr4[2] + xq[nt][3] * wr4[3];
            }
    }
    f32x4 lg0 = *(const f32x4*)&lng[g * 4];
    f32x4 lg1 = *(const f32x4*)&lng[16 + g * 4];
    f32x4 lb0 = *(const f32x4*)&lnb[g * 4];
    f32x4 lb1 = *(const f32x4*)&lnb[16 + g * 4];
#pragma unroll
    for (int nt = 0; nt < 4; ++nt) {
        float sy = 0.f, sy2 = 0.f;
#pragma unroll
        for (int mt = 0; mt < 2; ++mt)
#pragma unroll
            for (int r = 0; r < 4; ++r) {
                float v = yD[mt][nt][r];
                sy += v; sy2 += v * v;
            }
        sy  += __shfl_xor(sy, 16);  sy  += __shfl_xor(sy, 32);
        sy2 += __shfl_xor(sy2, 16); sy2 += __shfl_xor(sy2, 32);
        const float mu   = sy * (1.f / 32.f);
        const float var  = sy2 * (1.f / 32.f) - mu * mu;
        const float rstd = rsqrtf(var + 1e-5f);
#pragma unroll
        for (int r = 0; r < 4; ++r) {
            yD[0][nt][r] = (yD[0][nt][r] - mu) * rstd * lg0[r] + lb0[r];
            yD[1][nt][r] = (yD[1][nt][r] - mu) * rstd * lg1[r] + lb1[r];
        }
    }

    // ---- att_feat = mean over sq (register butterfly) ----
#pragma unroll
    for (int mt = 0; mt < 2; ++mt)
#pragma unroll
        for (int r = 0; r < 4; ++r) {
            float af = yD[mt][0][r] + yD[mt][1][r] + yD[mt][2][r] + yD[mt][3][r];
            af += __shfl_xor(af, 1);
            af += __shfl_xor(af, 2);
            af += __shfl_xor(af, 4);
            af += __shfl_xor(af, 8);
            if (fr == 0) smc[H + mt * 16 + g * 4 + r] = af * (1.f / 64.f);
        }
    wsync();

    // ================= DBMM fusion =================
    {
        const int j = s;
        float acc = gb[j];
        const f32x4* smc4 = (const f32x4*)smc;
        const f32x4* gw4  = (const f32x4*)&gw[j * 2 * H];
#pragma unroll
        for (int k4 = 0; k4 < 16; ++k4) {
            f32x4 cv = smc4[k4], wv4 = gw4[k4];
            acc += cv[0] * wv4[0] + cv[1] * wv4[1] + cv[2] * wv4[2] + cv[3] * wv4[3];
        }
        const float sig = 1.f / (1.f + __expf(-acc));
        smc[64 + j] = smc[j] * sig;
    }
    wsync();
    if (s < H) {
        float acc = pb[s];
        const f32x4* smc4 = (const f32x4*)(smc + 64);
        const f32x4* pw4  = (const f32x4*)&pw[s * 2 * H];
#pragma unroll
        for (int k4 = 0; k4 < 16; ++k4) {
            f32x4 cv = smc4[k4], wv4 = pw4[k4];
            acc += cv[0] * wv4[0] + cv[1] * wv4[1] + cv[2] * wv4[2] + cv[3] * wv4[3];
        }
        smc[128 + s] = acc;
    }
    wsync();
    if (s < 16) {
        float acc = h1b[s];
#pragma unroll
        for (int c = 0; c < H; ++c) acc += smc[128 + c] * h1w[s * H + c];
        smc[160 + s] = fmaxf(acc, 0.f);
    }
    wsync();
    if (s < 2) {
        float acc = h2b[s];
#pragma unroll
        for (int c = 0; c < 16; ++c) acc += smc[160 + c] * h2w[s * 16 + c];
        out[b * 2 + s] = acc;
    }
}

extern "C" void kernel_launch(void* const* d_in, const int* in_sizes, int n_in,
                              void* d_out, int out_size, void* d_ws, size_t ws_size,
                              hipStream_t stream) {
    (void)n_in; (void)d_ws; (void)ws_size; (void)in_sizes;
    const int nb = out_size / 2;   // B
    const float* xp_ = (const float*)d_in[0];
    const float* c1w = (const float*)d_in[1];  const float* c1b = (const float*)d_in[2];
    const float* c2w = (const float*)d_in[3];  const float* c2b = (const float*)d_in[4];
    const float* cpw = (const float*)d_in[5];  const float* cpb = (const float*)d_in[6];
    const float* ipw = (const float*)d_in[7];  const float* ipb = (const float*)d_in[8];
    const float* wq  = (const float*)d_in[9];  const float* bq  = (const float*)d_in[10];
    const float* wk  = (const float*)d_in[11]; const float* bk  = (const float*)d_in[12];
    const float* wv  = (const float*)d_in[13]; const float* bv  = (const float*)d_in[14];
    const float* wo  = (const float*)d_in[15]; const float* bo  = (const float*)d_in[16];
    const float* lng = (const float*)d_in[17]; const float* lnb = (const float*)d_in[18];
    const float* gw  = (const float*)d_in[19]; const float* gb  = (const float*)d_in[20];
    const float* pw  = (const float*)d_in[21]; const float* pb  = (const float*)d_in[22];
    const float* h1w = (const float*)d_in[23]; const float* h1b = (const float*)d_in[24];
    const float* h2w = (const float*)d_in[25]; const float* h2b = (const float*)d_in[26];
    float* outp = (float*)d_out;

    dim3 grid(nb / WPB), block(WPB * 64);
    hipLaunchKernelGGL(fused_fwd, grid, block, 0, stream,
                       xp_, c1w, c1b, c2w, c2b, cpw, cpb, ipw, ipb,
                       wq, bq, wk, bk, wv, bv, wo, bo, lng, lnb,
                       gw, gb, pw, pb, h1w, h1b, h2w, h2b, outp);
}